// Round 3
// baseline (241.439 us; speedup 1.0000x reference)
//
#include <hip/hip_runtime.h>
#include <math.h>

#define TOKENS 32768
#define KCODES 8192
#define DIM 32
#define NCHUNK 16
#define CPC 512                    // codes per chunk (per block)
#define GSZ 128                    // codes per stored-min group
#define NGROUPS 64                 // KCODES / GSZ
#define ZQ_ELEMS (TOKENS * DIM)
#define MARGIN 1e-3f               // screen-unit margin (>> 2*eps_screen ~ 2.4e-4)

typedef __attribute__((ext_vector_type(8))) short short8v;  // 8 bf16
typedef __attribute__((ext_vector_type(4))) float f32x4;

// round-to-nearest-even float bits -> bf16 bits (sign-magnitude safe)
__device__ inline unsigned rne16(unsigned u) {
  return (u + 0x7FFFu + ((u >> 16) & 1u)) >> 16;
}

// ---------------------------------------------------------------------------
// prep: w = -l2_normalize(emb row) split into 2 bf16 terms, stored in
// MFMA-A-fragment-linear layout; plus exact f64 per-row sum(e^2).
// ---------------------------------------------------------------------------
__global__ __launch_bounds__(256) void prep_codes(
    const float* __restrict__ emb, short* __restrict__ cA,
    short* __restrict__ cB, double* __restrict__ seArr) {
  int gid = blockIdx.x * 256 + threadIdx.x;  // 0..262143
  int code = gid >> 5;
  int k = gid & 31;
  float v = emb[gid];
  double dv = (double)v;
  double ds = dv * dv;
#pragma unroll
  for (int off = 16; off > 0; off >>= 1) ds += __shfl_xor(ds, off, 32);
  if (k == 0) seArr[code] = ds;
  float r = 1.0f / sqrtf((float)ds + 1e-12f);
  float w = -v * r;
  unsigned ua = rne16(__float_as_uint(w));
  float fa = __uint_as_float(ua << 16);
  unsigned ub = rne16(__float_as_uint(w - fa));
  int tile = code >> 4;
  int lane = (code & 15) | ((k >> 3) << 4);
  int off = tile * 512 + lane * 8 + (k & 7);
  cA[off] = (short)ua;
  cB[off] = (short)ub;
}

// ---------------------------------------------------------------------------
// screen: 3-term MFMA of s = z . (-e_n) (raw z).  Block = 4 waves x 64
// tokens; grid = (128 token-blocks, 16 chunks).  No LDS, no barriers —
// A-fragments streamed from global (L2-resident).  Stores per-(group,token)
// min screen value; group = 128 codes.
// ---------------------------------------------------------------------------
__global__ __launch_bounds__(256) void screen_kernel(
    const float* __restrict__ hs, const short* __restrict__ cA,
    const short* __restrict__ cB, float* __restrict__ pgmin) {
  int tid = threadIdx.x;
  int l = tid & 63;
  int w = tid >> 6;
  int g = l >> 4;
  int c16 = l & 15;
  int gt0 = blockIdx.x * 16 + w * 4;  // first token-tile of this wave
  int chunk = blockIdx.y;

  // token-side B fragments: raw z, 2-term bf16 split
  short8v zA[4], zB[4];
#pragma unroll
  for (int tt = 0; tt < 4; tt++) {
    int tok = (gt0 + tt) * 16 + c16;
    const float4* hp4 = (const float4*)(hs + (size_t)tok * DIM + g * 8);
    float4 q0 = hp4[0];
    float4 q1 = hp4[1];
    float x[8] = {q0.x, q0.y, q0.z, q0.w, q1.x, q1.y, q1.z, q1.w};
#pragma unroll
    for (int j = 0; j < 8; j++) {
      unsigned ua = rne16(__float_as_uint(x[j]));
      float fa = __uint_as_float(ua << 16);
      unsigned ub = rne16(__float_as_uint(x[j] - fa));
      zA[tt][j] = (short)ua;
      zB[tt][j] = (short)ub;
    }
  }

  int tbase = chunk * (CPC / 16);  // 32 tiles per chunk

  for (int grp = 0; grp < CPC / GSZ; grp++) {  // 4 groups of 128 codes
    float gm[4] = {3.4e38f, 3.4e38f, 3.4e38f, 3.4e38f};
#pragma unroll
    for (int ct = 0; ct < GSZ / 16; ct++) {  // 8 code-tiles
      int tile = tbase + grp * (GSZ / 16) + ct;
      short8v aA = *((const short8v*)(cA + (size_t)tile * 512) + l);
      short8v aB = *((const short8v*)(cB + (size_t)tile * 512) + l);
#pragma unroll
      for (int tt = 0; tt < 4; tt++) {
        f32x4 acc = {};
        acc = __builtin_amdgcn_mfma_f32_16x16x32_bf16(aA, zA[tt], acc, 0, 0, 0);
        acc = __builtin_amdgcn_mfma_f32_16x16x32_bf16(aA, zB[tt], acc, 0, 0, 0);
        acc = __builtin_amdgcn_mfma_f32_16x16x32_bf16(aB, zA[tt], acc, 0, 0, 0);
        float m = fminf(fminf(acc[0], acc[1]), fminf(acc[2], acc[3]));
        gm[tt] = fminf(gm[tt], m);
      }
    }
    int gidx = (chunk * (CPC / GSZ) + grp);
#pragma unroll
    for (int tt = 0; tt < 4; tt++) {
      float v = gm[tt];
      v = fminf(v, __shfl_xor(v, 16));
      v = fminf(v, __shfl_xor(v, 32));
      if (l < 16) {
        int tok = (gt0 + tt) * 16 + c16;
        pgmin[(size_t)gidx * TOKENS + tok] = v;
      }
    }
  }
}

// ---------------------------------------------------------------------------
// rescore: one wave per token.  Find min group-screen; rescore all codes of
// every group within MARGIN exactly in f64; exact argmin (+smallest-index
// tie-break).  Fused: write index, z_q = normalize(emb[idx]), loss partial.
// ---------------------------------------------------------------------------
__global__ __launch_bounds__(256) void rescore_kernel(
    const float* __restrict__ hs, const float* __restrict__ emb,
    const double* __restrict__ seArr, const float* __restrict__ pgmin,
    float* __restrict__ out, float* __restrict__ lossacc) {
  __shared__ float zsh[4][32];
  __shared__ float lred[4];
  int tid = threadIdx.x;
  int w = tid >> 6;
  int l = tid & 63;
  int tok = blockIdx.x * 4 + w;

  if (l < 32) zsh[w][l] = hs[(size_t)tok * DIM + l];
  __syncthreads();

  // z in f64 registers (full row per lane)
  double zd[32];
#pragma unroll
  for (int d = 0; d < 32; d++) zd[d] = (double)zsh[w][d];

  // sum(z^2) in f64 via 32-lane reduce (both halves hold same values)
  double p = (double)zsh[w][l & 31];
  p = p * p;
#pragma unroll
  for (int off = 1; off < 32; off <<= 1) p += __shfl_xor(p, off);
  double sz = p;
  double rz = 1.0 / sqrt(sz + 1e-12);

  // group minima
  float v = pgmin[(size_t)l * TOKENS + tok];
  float m = v;
#pragma unroll
  for (int off = 1; off < 64; off <<= 1) m = fminf(m, __shfl_xor(m, off));
  unsigned long long mask = __ballot(v <= m + MARGIN);

  double bestd = 1e300;
  int bestidx = 0x7fffffff;
  while (mask) {
    int grp = __ffsll(mask) - 1;
    mask &= mask - 1;
#pragma unroll
    for (int half = 0; half < 2; half++) {
      int c = grp * GSZ + half * 64 + l;
      const float4* ep = (const float4*)(emb + (size_t)c * DIM);
      double dot = 0.0;
#pragma unroll
      for (int j = 0; j < 8; j++) {
        float4 q = ep[j];
        dot += zd[4 * j] * (double)q.x;
        dot += zd[4 * j + 1] * (double)q.y;
        dot += zd[4 * j + 2] * (double)q.z;
        dot += zd[4 * j + 3] * (double)q.w;
      }
      double se = seArr[c];
      double re = 1.0 / sqrt(se + 1e-12);
      double D = sz * rz * rz + se * re * re - 2.0 * dot * rz * re;
      if (D < bestd || (D == bestd && c < bestidx)) {
        bestd = D;
        bestidx = c;
      }
    }
  }
  // wave argmin with index tie-break
#pragma unroll
  for (int off = 1; off < 64; off <<= 1) {
    double od = __shfl_xor(bestd, off);
    int oi = __shfl_xor(bestidx, off);
    if (od < bestd || (od == bestd && oi < bestidx)) {
      bestd = od;
      bestidx = oi;
    }
  }

  if (l == 0) out[(size_t)ZQ_ELEMS + tok] = (float)bestidx;

  // z_q + loss
  int d = l & 31;
  float ev = emb[(size_t)bestidx * DIM + d];
  double reW = 1.0 / sqrt(seArr[bestidx] + 1e-12);
  float zq = (float)((double)ev * reW);
  if (l < 32) out[(size_t)tok * DIM + d] = zq;
  double hn = zd[d] * rz;
  double diff = (double)zq - hn;
  double lp = (l < 32) ? diff * diff : 0.0;
#pragma unroll
  for (int off = 1; off < 64; off <<= 1) lp += __shfl_xor(lp, off);
  if (l == 0) lred[w] = (float)lp;
  __syncthreads();
  if (tid == 0) {
    float b = lred[0] + lred[1] + lred[2] + lred[3];
    atomicAdd(lossacc + (blockIdx.x & 127), b);
  }
}

// ---------------------------------------------------------------------------
// loss finalize: sum 128 partial slots, write both (identical) losses.
// ---------------------------------------------------------------------------
__global__ void loss_write_kernel(const float* __restrict__ lossacc,
                                  float* __restrict__ out) {
  int l = threadIdx.x;  // 64 threads
  float s = lossacc[l] + lossacc[l + 64];
#pragma unroll
  for (int off = 1; off < 64; off <<= 1) s += __shfl_xor(s, off);
  if (l == 0) {
    float v = s * (1.0f / (float)ZQ_ELEMS);
    out[ZQ_ELEMS + TOKENS] = v;
    out[ZQ_ELEMS + TOKENS + 1] = v;
  }
}

extern "C" void kernel_launch(void* const* d_in, const int* in_sizes, int n_in,
                              void* d_out, int out_size, void* d_ws,
                              size_t ws_size, hipStream_t stream) {
  const float* hs = (const float*)d_in[0];   // [32,1024,32]
  const float* emb = (const float*)d_in[1];  // [8192,32]
  float* out = (float*)d_out;
  char* ws = (char*)d_ws;

  short* cA = (short*)(ws);                        // 512 KB
  short* cB = (short*)(ws + 524288);               // 512 KB
  double* seArr = (double*)(ws + 1048576);         // 64 KB
  float* pgmin = (float*)(ws + 1114112);           // 8 MB: [64][32768]
  float* lossacc = (float*)(ws + 9502720);         // 512 B (128 slots)

  hipLaunchKernelGGL(prep_codes, dim3((KCODES * DIM) / 256), dim3(256), 0,
                     stream, emb, cA, cB, seArr);
  hipMemsetAsync(lossacc, 0, 512, stream);
  hipLaunchKernelGGL(screen_kernel, dim3(TOKENS / 256, NCHUNK), dim3(256), 0,
                     stream, hs, cA, cB, pgmin);
  hipLaunchKernelGGL(rescore_kernel, dim3(TOKENS / 4), dim3(256), 0, stream,
                     hs, emb, seArr, pgmin, out, lossacc);
  hipLaunchKernelGGL(loss_write_kernel, dim3(1), dim3(64), 0, stream, lossacc,
                     out);
}

// Round 4
// 134.007 us; speedup vs baseline: 1.8017x; 1.8017x over previous
//
#include <hip/hip_runtime.h>
#include <math.h>

#define TOKENS 32768
#define KCODES 8192
#define DIM 32
#define NCHUNK 16
#define CPC 512                    // codes per chunk (per screen block)
#define GSZ 128                    // codes per stored-min group
#define NGROUPS 64                 // KCODES / GSZ
#define RTOK 32                    // tokens per rescore block
#define ZQ_ELEMS (TOKENS * DIM)
#define MARGIN 1e-3f               // screen-unit margin (>> 2*eps_screen)

typedef __attribute__((ext_vector_type(8))) short short8v;  // 8 bf16
typedef __attribute__((ext_vector_type(4))) float f32x4;

// round-to-nearest-even float bits -> bf16 bits
__device__ inline unsigned rne16(unsigned u) {
  return (u + 0x7FFFu + ((u >> 16) & 1u)) >> 16;
}

// ---------------------------------------------------------------------------
// prep: w = -l2_normalize(emb row) split into 2 bf16 terms, stored in
// MFMA-A-fragment-linear layout; plus exact f64 per-row sum(e^2).
// ---------------------------------------------------------------------------
__global__ __launch_bounds__(256) void prep_codes(
    const float* __restrict__ emb, short* __restrict__ cA,
    short* __restrict__ cB, double* __restrict__ seArr) {
  int gid = blockIdx.x * 256 + threadIdx.x;  // 0..262143
  int code = gid >> 5;
  int k = gid & 31;
  float v = emb[gid];
  double dv = (double)v;
  double ds = dv * dv;
#pragma unroll
  for (int off = 16; off > 0; off >>= 1) ds += __shfl_xor(ds, off, 32);
  if (k == 0) seArr[code] = ds;
  float r = 1.0f / sqrtf((float)ds + 1e-12f);
  float w = -v * r;
  unsigned ua = rne16(__float_as_uint(w));
  float fa = __uint_as_float(ua << 16);
  unsigned ub = rne16(__float_as_uint(w - fa));
  int tile = code >> 4;
  int lane = (code & 15) | ((k >> 3) << 4);
  int off = tile * 512 + lane * 8 + (k & 7);
  cA[off] = (short)ua;
  cB[off] = (short)ub;
}

// ---------------------------------------------------------------------------
// screen: 3-term MFMA of s = z . (-e_n) (raw z).  Block = 4 waves x 64
// tokens; grid = (128 token-blocks, 16 chunks).  No LDS, no barriers.
// Stores per-(group,token) min screen value; group = 128 codes.
// ---------------------------------------------------------------------------
__global__ __launch_bounds__(256) void screen_kernel(
    const float* __restrict__ hs, const short* __restrict__ cA,
    const short* __restrict__ cB, float* __restrict__ pgmin) {
  int tid = threadIdx.x;
  int l = tid & 63;
  int w = tid >> 6;
  int g = l >> 4;
  int c16 = l & 15;
  int gt0 = blockIdx.x * 16 + w * 4;  // first token-tile of this wave
  int chunk = blockIdx.y;

  // token-side B fragments: raw z, 2-term bf16 split
  short8v zA[4], zB[4];
#pragma unroll
  for (int tt = 0; tt < 4; tt++) {
    int tok = (gt0 + tt) * 16 + c16;
    const float4* hp4 = (const float4*)(hs + (size_t)tok * DIM + g * 8);
    float4 q0 = hp4[0];
    float4 q1 = hp4[1];
    float x[8] = {q0.x, q0.y, q0.z, q0.w, q1.x, q1.y, q1.z, q1.w};
#pragma unroll
    for (int j = 0; j < 8; j++) {
      unsigned ua = rne16(__float_as_uint(x[j]));
      float fa = __uint_as_float(ua << 16);
      unsigned ub = rne16(__float_as_uint(x[j] - fa));
      zA[tt][j] = (short)ua;
      zB[tt][j] = (short)ub;
    }
  }

  int tbase = chunk * (CPC / 16);  // 32 tiles per chunk

  for (int grp = 0; grp < CPC / GSZ; grp++) {  // 4 groups of 128 codes
    float gm[4] = {3.4e38f, 3.4e38f, 3.4e38f, 3.4e38f};
#pragma unroll
    for (int ct = 0; ct < GSZ / 16; ct++) {  // 8 code-tiles
      int tile = tbase + grp * (GSZ / 16) + ct;
      short8v aA = *((const short8v*)(cA + (size_t)tile * 512) + l);
      short8v aB = *((const short8v*)(cB + (size_t)tile * 512) + l);
#pragma unroll
      for (int tt = 0; tt < 4; tt++) {
        f32x4 acc = {};
        acc = __builtin_amdgcn_mfma_f32_16x16x32_bf16(aA, zA[tt], acc, 0, 0, 0);
        acc = __builtin_amdgcn_mfma_f32_16x16x32_bf16(aA, zB[tt], acc, 0, 0, 0);
        acc = __builtin_amdgcn_mfma_f32_16x16x32_bf16(aB, zA[tt], acc, 0, 0, 0);
        float m = fminf(fminf(acc[0], acc[1]), fminf(acc[2], acc[3]));
        gm[tt] = fminf(gm[tt], m);
      }
    }
    int gidx = (chunk * (CPC / GSZ) + grp);
#pragma unroll
    for (int tt = 0; tt < 4; tt++) {
      float v = gm[tt];
      v = fminf(v, __shfl_xor(v, 16));
      v = fminf(v, __shfl_xor(v, 32));
      if (l < 16) {
        int tok = (gt0 + tt) * 16 + c16;
        pgmin[(size_t)gidx * TOKENS + tok] = v;
      }
    }
  }
}

// ---------------------------------------------------------------------------
// rescore: block = 4 waves, 32 tokens.  Stage pgmin[64][32] (coalesced rows)
// and z rows into LDS.  Per token (8 per wave, serial): candidate groups
// within MARGIN of the min group-screen -> exact f64 rescore of those codes,
// exact argmin (+smallest-index tie-break), fused z_q gather/normalize,
// index write, loss partial.  NOTE: zd[] is only ever indexed with
// compile-time constants (rule #20); the loss path reads z from LDS.
// ---------------------------------------------------------------------------
__global__ __launch_bounds__(256) void rescore_kernel(
    const float* __restrict__ hs, const float* __restrict__ emb,
    const double* __restrict__ seArr, const float* __restrict__ pgmin,
    float* __restrict__ out, float* __restrict__ lossacc) {
  __shared__ float pg[NGROUPS][RTOK + 1];  // [grp][tok], padded
  __shared__ float zsh[RTOK][32];
  __shared__ float lred[4];
  int tid = threadIdx.x;
  int w = tid >> 6;
  int l = tid & 63;
  int tok0 = blockIdx.x * RTOK;

  // stage pgmin (rows contiguous in [grp][tok] layout -> coalesced)
  for (int i = tid; i < NGROUPS * RTOK; i += 256) {
    int grp = i >> 5;
    int tk = i & 31;
    pg[grp][tk] = pgmin[(size_t)grp * TOKENS + tok0 + tk];
  }
  // stage z rows (contiguous)
  for (int i = tid; i < RTOK * 32; i += 256)
    zsh[i >> 5][i & 31] = hs[(size_t)tok0 * 32 + i];
  __syncthreads();

  float wloss = 0.f;
  for (int t8 = 0; t8 < RTOK / 4; t8++) {
    int tl = w * (RTOK / 4) + t8;  // local token 0..31
    int tok = tok0 + tl;

    // z into registers (compile-time indexed only)
    float zf[32];
#pragma unroll
    for (int j = 0; j < 8; j++) {
      float4 q = *(const float4*)&zsh[tl][4 * j];
      zf[4 * j] = q.x; zf[4 * j + 1] = q.y;
      zf[4 * j + 2] = q.z; zf[4 * j + 3] = q.w;
    }
    double zd[32];
    double sz = 0.0;
#pragma unroll
    for (int d = 0; d < 32; d++) {
      zd[d] = (double)zf[d];
      sz += zd[d] * zd[d];
    }
    double rz = 1.0 / sqrt(sz + 1e-12);

    float v = pg[l][tl];
    float m = v;
#pragma unroll
    for (int off = 1; off < 64; off <<= 1) m = fminf(m, __shfl_xor(m, off));
    unsigned long long mask = __ballot(v <= m + MARGIN);

    double bestd = 1e300;
    int bestidx = 0x7fffffff;
    while (mask) {
      int grp = __ffsll(mask) - 1;
      mask &= mask - 1;
#pragma unroll
      for (int half = 0; half < 2; half++) {
        int c = grp * GSZ + half * 64 + l;
        const float4* ep = (const float4*)(emb + (size_t)c * DIM);
        double dot = 0.0;
#pragma unroll
        for (int j = 0; j < 8; j++) {
          float4 q = ep[j];
          dot += zd[4 * j] * (double)q.x + zd[4 * j + 1] * (double)q.y +
                 zd[4 * j + 2] * (double)q.z + zd[4 * j + 3] * (double)q.w;
        }
        double se = seArr[c];
        double re = 1.0 / sqrt(se + 1e-12);
        double D = sz * rz * rz + se * re * re - 2.0 * dot * rz * re;
        if (D < bestd || (D == bestd && c < bestidx)) {
          bestd = D;
          bestidx = c;
        }
      }
    }
#pragma unroll
    for (int off = 1; off < 64; off <<= 1) {
      double od = __shfl_xor(bestd, off);
      int oi = __shfl_xor(bestidx, off);
      if (od < bestd || (od == bestd && oi < bestidx)) {
        bestd = od;
        bestidx = oi;
      }
    }

    if (l == 0) out[(size_t)ZQ_ELEMS + tok] = (float)bestidx;

    // z_q + loss (lanes 0..31 active; z read from LDS, not zd[])
    int d = l & 31;
    float ev = emb[(size_t)bestidx * DIM + d];
    double reW = 1.0 / sqrt(seArr[bestidx] + 1e-12);
    float zq = (float)((double)ev * reW);
    double hn = (double)zsh[tl][d] * rz;
    double diff = (double)zq - hn;
    float lp = (l < 32) ? (float)(diff * diff) : 0.f;
    if (l < 32) out[(size_t)tok * DIM + d] = zq;
#pragma unroll
    for (int off = 1; off < 64; off <<= 1) lp += __shfl_xor(lp, off);
    wloss += lp;
  }
  if (l == 0) lred[w] = wloss;
  __syncthreads();
  if (tid == 0)
    atomicAdd(lossacc + (blockIdx.x & 127),
              lred[0] + lred[1] + lred[2] + lred[3]);
}

// ---------------------------------------------------------------------------
// loss finalize: sum 128 partial slots, write both (identical) losses.
// ---------------------------------------------------------------------------
__global__ void loss_write_kernel(const float* __restrict__ lossacc,
                                  float* __restrict__ out) {
  int l = threadIdx.x;  // 64 threads
  float s = lossacc[l] + lossacc[l + 64];
#pragma unroll
  for (int off = 1; off < 64; off <<= 1) s += __shfl_xor(s, off);
  if (l == 0) {
    float v = s * (1.0f / (float)ZQ_ELEMS);
    out[ZQ_ELEMS + TOKENS] = v;
    out[ZQ_ELEMS + TOKENS + 1] = v;
  }
}

extern "C" void kernel_launch(void* const* d_in, const int* in_sizes, int n_in,
                              void* d_out, int out_size, void* d_ws,
                              size_t ws_size, hipStream_t stream) {
  const float* hs = (const float*)d_in[0];   // [32,1024,32]
  const float* emb = (const float*)d_in[1];  // [8192,32]
  float* out = (float*)d_out;
  char* ws = (char*)d_ws;

  short* cA = (short*)(ws);                        // 512 KB
  short* cB = (short*)(ws + 524288);               // 512 KB
  double* seArr = (double*)(ws + 1048576);         // 64 KB
  float* pgmin = (float*)(ws + 1114112);           // 8 MB: [64][32768]
  float* lossacc = (float*)(ws + 9502720);         // 512 B (128 slots)

  hipLaunchKernelGGL(prep_codes, dim3((KCODES * DIM) / 256), dim3(256), 0,
                     stream, emb, cA, cB, seArr);
  hipMemsetAsync(lossacc, 0, 512, stream);
  hipLaunchKernelGGL(screen_kernel, dim3(TOKENS / 256, NCHUNK), dim3(256), 0,
                     stream, hs, cA, cB, pgmin);
  hipLaunchKernelGGL(rescore_kernel, dim3(TOKENS / RTOK), dim3(256), 0, stream,
                     hs, emb, seArr, pgmin, out, lossacc);
  hipLaunchKernelGGL(loss_write_kernel, dim3(1), dim3(64), 0, stream, lossacc,
                     out);
}